// Round 3
// baseline (308.620 us; speedup 1.0000x reference)
//
#include <hip/hip_runtime.h>
#include <math.h>

#define BATCH 256
#define NHALF 2048
#define DK 64
#define SPLIT 4
#define NBLK (BATCH * 2 * SPLIT)            // 2048
#define ROWS_PER_BLOCK (NHALF / SPLIT)      // 512
#define ROWS_PER_WAVE  (ROWS_PER_BLOCK / 4) // 128
#define PART_STRIDE 320
#define CNT_OFF_BYTES ((size_t)NBLK * PART_STRIDE * 4)   // 2,621,440

__device__ __forceinline__ float rcp_fast(float x)  { return __builtin_amdgcn_rcpf(x); }
__device__ __forceinline__ float exp2_fast(float x) { return __builtin_amdgcn_exp2f(x); }

// Fused kernel. Per (b, half, slice) block accumulates, per k = sub+16j:
//   accq[k]  = sum_n softmax_k(x Wq + bq)[n,k]
//   ek[k]    = sum_n exp((x Wk + bk)[n,k])
//   exv[k,d] = sum_n exp((x Wk + bk)[n,k]) * x[n,d]      (Wv applied at the end:
//              ekv[k,v] = sum_d exv[k,d]*Wv[d,v] + bv[v]*ek[k])
// log2e is folded into the Wq/Wk/bq/bk copies so exp = raw v_exp_f32.
// 8 rows per iteration: two independent 4-row shuffle chains for ILP.
// The last block per b (device-scope counter) does the final combine.
__global__ __launch_bounds__(256) void ea_fused(
    const float* __restrict__ inp,
    const float* __restrict__ Wq, const float* __restrict__ bq,
    const float* __restrict__ Wk, const float* __restrict__ bk,
    const float* __restrict__ Wv, const float* __restrict__ bv,
    float* __restrict__ ws, unsigned* __restrict__ cnt,
    float* __restrict__ out)
{
    const int blk   = blockIdx.x;
    const int b     = blk >> 3;     // / (2*SPLIT)
    const int rem   = blk & 7;
    const int half  = rem >> 2;
    const int slice = rem & 3;

    const int tid  = threadIdx.x;
    const int w    = tid >> 6;
    const int lane = tid & 63;
    const int g    = lane >> 4;   // row-group 0..3
    const int sub  = lane & 15;

    const float LOG2E = 1.4426950408889634f;
    float wq0[4], wq1[4], wq2[4], bqv[4];
    float wk0[4], wk1[4], wk2[4], bkv[4];
#pragma unroll
    for (int j = 0; j < 4; ++j) {
        int k = sub + 16 * j;
        wq0[j] = Wq[k] * LOG2E; wq1[j] = Wq[64 + k] * LOG2E; wq2[j] = Wq[128 + k] * LOG2E;
        bqv[j] = bq[k] * LOG2E;
        wk0[j] = Wk[k] * LOG2E; wk1[j] = Wk[64 + k] * LOG2E; wk2[j] = Wk[128 + k] * LOG2E;
        bkv[j] = bk[k] * LOG2E;
    }

    float accq[4] = {0,0,0,0}, ek[4] = {0,0,0,0};
    float ex0[4] = {0,0,0,0}, ex1[4] = {0,0,0,0}, ex2[4] = {0,0,0,0};

    const float* xp = inp
        + ((size_t)b * (2 * NHALF) + (size_t)half * NHALF
           + (size_t)slice * ROWS_PER_BLOCK + (size_t)w * ROWS_PER_WAVE + g) * 3;

    for (int i = 0; i < ROWS_PER_WAVE; i += 8) {
        const float a0 = xp[0],  a1 = xp[1],  a2 = xp[2];    // row i+g
        const float c0 = xp[12], c1 = xp[13], c2 = xp[14];   // row i+4+g
        xp += 24;

        float eqA[4], eqB[4];
        float rsA = 0.f, rsB = 0.f;
#pragma unroll
        for (int j = 0; j < 4; ++j) {
            eqA[j] = exp2_fast(fmaf(a0, wq0[j], fmaf(a1, wq1[j], fmaf(a2, wq2[j], bqv[j]))));
            rsA += eqA[j];
            eqB[j] = exp2_fast(fmaf(c0, wq0[j], fmaf(c1, wq1[j], fmaf(c2, wq2[j], bqv[j]))));
            rsB += eqB[j];
        }
        rsA += __shfl_xor(rsA, 1);  rsB += __shfl_xor(rsB, 1);
        rsA += __shfl_xor(rsA, 2);  rsB += __shfl_xor(rsB, 2);
        rsA += __shfl_xor(rsA, 4);  rsB += __shfl_xor(rsB, 4);
        rsA += __shfl_xor(rsA, 8);  rsB += __shfl_xor(rsB, 8);
        const float invA = rcp_fast(rsA);
        const float invB = rcp_fast(rsB);

#pragma unroll
        for (int j = 0; j < 4; ++j) {
            accq[j] = fmaf(eqA[j], invA, fmaf(eqB[j], invB, accq[j]));
            float eA = exp2_fast(fmaf(a0, wk0[j], fmaf(a1, wk1[j], fmaf(a2, wk2[j], bkv[j]))));
            float eB = exp2_fast(fmaf(c0, wk0[j], fmaf(c1, wk1[j], fmaf(c2, wk2[j], bkv[j]))));
            ek[j]  += eA + eB;
            ex0[j] = fmaf(eA, a0, fmaf(eB, c0, ex0[j]));
            ex1[j] = fmaf(eA, a1, fmaf(eB, c1, ex1[j]));
            ex2[j] = fmaf(eA, a2, fmaf(eB, c2, ex2[j]));
        }
    }

    // reduce across the 4 row-groups within the wave (xor 16, 32)
#pragma unroll
    for (int j = 0; j < 4; ++j) {
        accq[j] += __shfl_xor(accq[j], 16); accq[j] += __shfl_xor(accq[j], 32);
        ek[j]   += __shfl_xor(ek[j], 16);   ek[j]   += __shfl_xor(ek[j], 32);
        ex0[j]  += __shfl_xor(ex0[j], 16);  ex0[j]  += __shfl_xor(ex0[j], 32);
        ex1[j]  += __shfl_xor(ex1[j], 16);  ex1[j]  += __shfl_xor(ex1[j], 32);
        ex2[j]  += __shfl_xor(ex2[j], 16);  ex2[j]  += __shfl_xor(ex2[j], 32);
    }

    __shared__ float lds[4][PART_STRIDE];
    __shared__ int isLast;
    if (g == 0) {
#pragma unroll
        for (int j = 0; j < 4; ++j) {
            int k = sub + 16 * j;
            lds[w][k]       = accq[j];
            lds[w][64 + k]  = ek[j];
            lds[w][128 + k] = ex0[j];
            lds[w][192 + k] = ex1[j];
            lds[w][256 + k] = ex2[j];
        }
    }
    __syncthreads();

    // NOTE: strided loop — PART_STRIDE (320) > blockDim (256). R2's
    // `if (tid < PART_STRIDE)` left slots 256..319 unwritten (poison) → absmax 1.8.
    float* op = ws + (size_t)blk * PART_STRIDE;
    for (int idx = tid; idx < PART_STRIDE; idx += 256)
        op[idx] = lds[0][idx] + lds[1][idx] + lds[2][idx] + lds[3][idx];

    __threadfence();   // release partial stores to device scope
    __syncthreads();
    if (tid == 0) {
        unsigned old = __hip_atomic_fetch_add(&cnt[b], 1u, __ATOMIC_ACQ_REL,
                                              __HIP_MEMORY_SCOPE_AGENT);
        isLast = (old == 2 * SPLIT - 1) ? 1 : 0;
    }
    __syncthreads();

    if (isLast && tid < 64) {
        __threadfence();   // acquire: make other blocks' partials visible
        float wv[9], bvv[3];
#pragma unroll
        for (int i = 0; i < 9; ++i) wv[i] = Wv[i];
#pragma unroll
        for (int i = 0; i < 3; ++i) bvv[i] = bv[i];

        const float* basep = ws + (size_t)b * (2 * SPLIT) * PART_STRIDE;
        float res[2][3];
#pragma unroll
        for (int h = 0; h < 2; ++h) {
            float aq = 0.f, ekk = 0.f, e0 = 0.f, e1 = 0.f, e2 = 0.f;
#pragma unroll
            for (int s = 0; s < SPLIT; ++s) {
                const float* p = basep + (size_t)(h * SPLIT + s) * PART_STRIDE;
                aq  += p[tid];
                ekk += p[64 + tid];
                e0  += p[128 + tid];
                e1  += p[192 + tid];
                e2  += p[256 + tid];
            }
            const float r = aq / ((float)NHALF * ekk);
            float c0 = fmaf(e0, wv[0], fmaf(e1, wv[3], fmaf(e2, wv[6], bvv[0] * ekk)));
            float c1 = fmaf(e0, wv[1], fmaf(e1, wv[4], fmaf(e2, wv[7], bvv[1] * ekk)));
            float c2 = fmaf(e0, wv[2], fmaf(e1, wv[5], fmaf(e2, wv[8], bvv[2] * ekk)));
            float p0 = r * c0, p1 = r * c1, p2 = r * c2;
            for (int m = 1; m < 64; m <<= 1) {
                p0 += __shfl_xor(p0, m);
                p1 += __shfl_xor(p1, m);
                p2 += __shfl_xor(p2, m);
            }
            res[h][0] = p0; res[h][1] = p1; res[h][2] = p2;
        }
        const float a0 = 0.5f * (res[0][0] + res[1][0]);
        const float a1 = 0.5f * (res[0][1] + res[1][1]);
        const float a2 = 0.5f * (res[0][2] + res[1][2]);
        const float nrm = rsqrtf(fmaf(a0, a0, fmaf(a1, a1, a2 * a2)));
        if (tid == 0) {
            out[(size_t)b * 3 + 0] = a0 * nrm;
            out[(size_t)b * 3 + 1] = a1 * nrm;
            out[(size_t)b * 3 + 2] = a2 * nrm;
        }
    }
}

extern "C" void kernel_launch(void* const* d_in, const int* in_sizes, int n_in,
                              void* d_out, int out_size, void* d_ws, size_t ws_size,
                              hipStream_t stream) {
    const float* inp = (const float*)d_in[0];
    const float* Wq  = (const float*)d_in[1];
    const float* bq  = (const float*)d_in[2];
    const float* Wk  = (const float*)d_in[3];
    const float* bk  = (const float*)d_in[4];
    const float* Wv  = (const float*)d_in[5];
    const float* bv  = (const float*)d_in[6];
    float*    ws  = (float*)d_ws;
    unsigned* cnt = (unsigned*)((char*)d_ws + CNT_OFF_BYTES);
    float*    out = (float*)d_out;

    hipMemsetAsync(cnt, 0, BATCH * sizeof(unsigned), stream);
    hipLaunchKernelGGL(ea_fused, dim3(NBLK), dim3(256), 0, stream,
                       inp, Wq, bq, Wk, bk, Wv, bv, ws, cnt, out);
}

// Round 4
// 105.982 us; speedup vs baseline: 2.9120x; 2.9120x over previous
//
#include <hip/hip_runtime.h>
#include <math.h>

#define BATCH 256
#define NHALF 2048
#define DK 64
#define PART 320   // 5 * 64 partial values per (half-stream)

__device__ __forceinline__ float rcp_fast(float x)  { return __builtin_amdgcn_rcpf(x); }
__device__ __forceinline__ float exp2_fast(float x) { return __builtin_amdgcn_exp2f(x); }

// One block per batch element b. 1024 threads = 16 waves; wave w handles
// half = w>>3, row-slice = w&7 (256 rows/wave). Within a wave: 16 lanes per
// row, each lane owns k = sub + 16j (j=0..3); 8 rows per iteration as two
// independent 4-row shuffle chains. Accumulates (per k):
//   accq[k]  = sum_n softmax_k(x Wq + bq)[n,k]
//   ek[k]    = sum_n exp((x Wk + bk)[n,k])
//   ex[k,d]  = sum_n exp((x Wk + bk)[n,k]) * x[n,d]   (Wv applied once at end)
// log2e folded into Wq/Wk/bq/bk so exp = raw v_exp_f32. All reduction is
// intra-block (LDS) — no inter-block fences (R3 showed agent-scope fences
// thrash per-XCD L2s: VALUBusy 64%->10%).
__global__ __launch_bounds__(1024) void ea_onepass(
    const float* __restrict__ inp,
    const float* __restrict__ Wq, const float* __restrict__ bq,
    const float* __restrict__ Wk, const float* __restrict__ bk,
    const float* __restrict__ Wv, const float* __restrict__ bv,
    float* __restrict__ out)
{
    const int b      = blockIdx.x;
    const int tid    = threadIdx.x;
    const int w      = tid >> 6;    // wave 0..15
    const int lane   = tid & 63;
    const int g      = lane >> 4;   // row-group 0..3
    const int sub    = lane & 15;
    const int half   = w >> 3;
    const int wslice = w & 7;

    const float LOG2E = 1.4426950408889634f;
    float wq0[4], wq1[4], wq2[4], bqv[4];
    float wk0[4], wk1[4], wk2[4], bkv[4];
#pragma unroll
    for (int j = 0; j < 4; ++j) {
        int k = sub + 16 * j;
        wq0[j] = Wq[k] * LOG2E; wq1[j] = Wq[64 + k] * LOG2E; wq2[j] = Wq[128 + k] * LOG2E;
        bqv[j] = bq[k] * LOG2E;
        wk0[j] = Wk[k] * LOG2E; wk1[j] = Wk[64 + k] * LOG2E; wk2[j] = Wk[128 + k] * LOG2E;
        bkv[j] = bk[k] * LOG2E;
    }

    float accq[4] = {0,0,0,0}, ek[4] = {0,0,0,0};
    float ex0[4] = {0,0,0,0}, ex1[4] = {0,0,0,0}, ex2[4] = {0,0,0,0};

    // rows for this wave: half*NHALF + wslice*256 + {i+g, i+4+g}, i += 8
    const float* xp = inp
        + ((size_t)b * (2 * NHALF) + (size_t)half * NHALF
           + (size_t)wslice * 256 + g) * 3;

    for (int i = 0; i < 256; i += 8) {
        const float a0 = xp[0],  a1 = xp[1],  a2 = xp[2];    // row i+g
        const float c0 = xp[12], c1 = xp[13], c2 = xp[14];   // row i+4+g
        xp += 24;

        float eqA[4], eqB[4];
        float rsA = 0.f, rsB = 0.f;
#pragma unroll
        for (int j = 0; j < 4; ++j) {
            eqA[j] = exp2_fast(fmaf(a0, wq0[j], fmaf(a1, wq1[j], fmaf(a2, wq2[j], bqv[j]))));
            rsA += eqA[j];
            eqB[j] = exp2_fast(fmaf(c0, wq0[j], fmaf(c1, wq1[j], fmaf(c2, wq2[j], bqv[j]))));
            rsB += eqB[j];
        }
        rsA += __shfl_xor(rsA, 1);  rsB += __shfl_xor(rsB, 1);
        rsA += __shfl_xor(rsA, 2);  rsB += __shfl_xor(rsB, 2);
        rsA += __shfl_xor(rsA, 4);  rsB += __shfl_xor(rsB, 4);
        rsA += __shfl_xor(rsA, 8);  rsB += __shfl_xor(rsB, 8);
        const float invA = rcp_fast(rsA);
        const float invB = rcp_fast(rsB);

#pragma unroll
        for (int j = 0; j < 4; ++j) {
            accq[j] = fmaf(eqA[j], invA, fmaf(eqB[j], invB, accq[j]));
            float eA = exp2_fast(fmaf(a0, wk0[j], fmaf(a1, wk1[j], fmaf(a2, wk2[j], bkv[j]))));
            float eB = exp2_fast(fmaf(c0, wk0[j], fmaf(c1, wk1[j], fmaf(c2, wk2[j], bkv[j]))));
            ek[j]  += eA + eB;
            ex0[j] = fmaf(eA, a0, fmaf(eB, c0, ex0[j]));
            ex1[j] = fmaf(eA, a1, fmaf(eB, c1, ex1[j]));
            ex2[j] = fmaf(eA, a2, fmaf(eB, c2, ex2[j]));
        }
    }

    // reduce across the 4 row-groups within the wave
#pragma unroll
    for (int j = 0; j < 4; ++j) {
        accq[j] += __shfl_xor(accq[j], 16); accq[j] += __shfl_xor(accq[j], 32);
        ek[j]   += __shfl_xor(ek[j], 16);   ek[j]   += __shfl_xor(ek[j], 32);
        ex0[j]  += __shfl_xor(ex0[j], 16);  ex0[j]  += __shfl_xor(ex0[j], 32);
        ex1[j]  += __shfl_xor(ex1[j], 16);  ex1[j]  += __shfl_xor(ex1[j], 32);
        ex2[j]  += __shfl_xor(ex2[j], 16);  ex2[j]  += __shfl_xor(ex2[j], 32);
    }

    __shared__ float lds[16][PART];   // per-wave partials
    __shared__ float red[2][PART];    // per-half sums
    if (g == 0) {
#pragma unroll
        for (int j = 0; j < 4; ++j) {
            int k = sub + 16 * j;
            lds[w][k]       = accq[j];
            lds[w][64 + k]  = ek[j];
            lds[w][128 + k] = ex0[j];
            lds[w][192 + k] = ex1[j];
            lds[w][256 + k] = ex2[j];
        }
    }
    __syncthreads();

    // stage 2: sum the 8 wave-slots of each half (lane t -> column t: stride-1,
    // conflict-free)
    if (tid < PART) {
        float s0 = 0.f, s1 = 0.f;
#pragma unroll
        for (int p = 0; p < 8; ++p) {
            s0 += lds[p][tid];
            s1 += lds[8 + p][tid];
        }
        red[0][tid] = s0;
        red[1][tid] = s1;
    }
    __syncthreads();

    // finish: one wave computes both halves, combines, normalizes
    if (tid < 64) {
        float wv[9], bvv[3];
#pragma unroll
        for (int i = 0; i < 9; ++i) wv[i] = Wv[i];
#pragma unroll
        for (int i = 0; i < 3; ++i) bvv[i] = bv[i];

        float res[2][3];
#pragma unroll
        for (int h = 0; h < 2; ++h) {
            const float aq  = red[h][tid];
            const float ekk = red[h][64 + tid];
            const float e0  = red[h][128 + tid];
            const float e1  = red[h][192 + tid];
            const float e2  = red[h][256 + tid];
            const float r = aq / ((float)NHALF * ekk);
            float c0 = fmaf(e0, wv[0], fmaf(e1, wv[3], fmaf(e2, wv[6], bvv[0] * ekk)));
            float c1 = fmaf(e0, wv[1], fmaf(e1, wv[4], fmaf(e2, wv[7], bvv[1] * ekk)));
            float c2 = fmaf(e0, wv[2], fmaf(e1, wv[5], fmaf(e2, wv[8], bvv[2] * ekk)));
            float p0 = r * c0, p1 = r * c1, p2 = r * c2;
            for (int m = 1; m < 64; m <<= 1) {
                p0 += __shfl_xor(p0, m);
                p1 += __shfl_xor(p1, m);
                p2 += __shfl_xor(p2, m);
            }
            res[h][0] = p0; res[h][1] = p1; res[h][2] = p2;
        }
        const float a0 = 0.5f * (res[0][0] + res[1][0]);
        const float a1 = 0.5f * (res[0][1] + res[1][1]);
        const float a2 = 0.5f * (res[0][2] + res[1][2]);
        const float nrm = rsqrtf(fmaf(a0, a0, fmaf(a1, a1, a2 * a2)));
        if (tid == 0) {
            out[(size_t)b * 3 + 0] = a0 * nrm;
            out[(size_t)b * 3 + 1] = a1 * nrm;
            out[(size_t)b * 3 + 2] = a2 * nrm;
        }
    }
}

extern "C" void kernel_launch(void* const* d_in, const int* in_sizes, int n_in,
                              void* d_out, int out_size, void* d_ws, size_t ws_size,
                              hipStream_t stream) {
    const float* inp = (const float*)d_in[0];
    const float* Wq  = (const float*)d_in[1];
    const float* bq  = (const float*)d_in[2];
    const float* Wk  = (const float*)d_in[3];
    const float* bk  = (const float*)d_in[4];
    const float* Wv  = (const float*)d_in[5];
    const float* bv  = (const float*)d_in[6];
    float* out = (float*)d_out;

    hipLaunchKernelGGL(ea_onepass, dim3(BATCH), dim3(1024), 0, stream,
                       inp, Wq, bq, Wk, bk, Wv, bv, out);
}

// Round 5
// 101.984 us; speedup vs baseline: 3.0262x; 1.0392x over previous
//
#include <hip/hip_runtime.h>
#include <math.h>

#define BATCH 256
#define NHALF 2048
#define DK 64
#define SPLIT 4
#define NBLK (BATCH * 2 * SPLIT)            // 2048
#define ROWS_PER_BLOCK (NHALF / SPLIT)      // 512
#define ROWS_PER_WAVE  (ROWS_PER_BLOCK / 4) // 128
#define PART 320

typedef float v2f __attribute__((ext_vector_type(2)));
#define PKFMA(a, b, c) __builtin_elementwise_fma((a), (b), (c))

__device__ __forceinline__ float rcp_fast(float x)  { return __builtin_amdgcn_rcpf(x); }
__device__ __forceinline__ float exp2_fast(float x) { return __builtin_amdgcn_exp2f(x); }
__device__ __forceinline__ float redg(float v) {     // reduce across the 4 row-groups
    v += __shfl_xor(v, 16);
    v += __shfl_xor(v, 32);
    return v;
}

// Partial kernel: per (b, half, slice) block (2048 blocks x 256 thr = 4 waves).
// 16 lanes per row; lane owns k = sub+16j, j packed in pairs (j=2p, 2p+1) as
// float2 so logits/accums use v_pk_fma_f32. 8 rows/iter (two shuffle chains).
// Accumulates per k: accq = sum_n softmax_k(q); ek = sum_n exp(k);
// ex[d] = sum_n exp(k)*x[d] (Wv applied in finisher). log2e folded into
// weights so exp = raw v_exp_f32. No inter-block fences (R3 lesson).
__global__ __launch_bounds__(256) void ea_partial_pk(
    const float* __restrict__ inp,
    const float* __restrict__ Wq, const float* __restrict__ bq,
    const float* __restrict__ Wk, const float* __restrict__ bk,
    float* __restrict__ ws)
{
    const int blk   = blockIdx.x;
    const int b     = blk >> 3;
    const int rem   = blk & 7;
    const int half  = rem >> 2;
    const int slice = rem & 3;

    const int tid  = threadIdx.x;
    const int w    = tid >> 6;
    const int lane = tid & 63;
    const int g    = lane >> 4;
    const int sub  = lane & 15;

    const float LOG2E = 1.4426950408889634f;
    v2f wq0p[2], wq1p[2], wq2p[2], bqp[2];
    v2f wk0p[2], wk1p[2], wk2p[2], bkp[2];
#pragma unroll
    for (int p = 0; p < 2; ++p) {
        const int klo = sub + 32 * p, khi = klo + 16;
        wq0p[p] = (v2f){Wq[klo],       Wq[khi]}       * LOG2E;
        wq1p[p] = (v2f){Wq[64 + klo],  Wq[64 + khi]}  * LOG2E;
        wq2p[p] = (v2f){Wq[128 + klo], Wq[128 + khi]} * LOG2E;
        bqp[p]  = (v2f){bq[klo],       bq[khi]}       * LOG2E;
        wk0p[p] = (v2f){Wk[klo],       Wk[khi]}       * LOG2E;
        wk1p[p] = (v2f){Wk[64 + klo],  Wk[64 + khi]}  * LOG2E;
        wk2p[p] = (v2f){Wk[128 + klo], Wk[128 + khi]} * LOG2E;
        bkp[p]  = (v2f){bk[klo],       bk[khi]}       * LOG2E;
    }

    v2f accqp[2] = {{0,0},{0,0}}, ekp[2] = {{0,0},{0,0}};
    v2f ex0p[2] = {{0,0},{0,0}}, ex1p[2] = {{0,0},{0,0}}, ex2p[2] = {{0,0},{0,0}};

    const float* xp = inp
        + ((size_t)b * (2 * NHALF) + (size_t)half * NHALF
           + (size_t)slice * ROWS_PER_BLOCK + (size_t)w * ROWS_PER_WAVE + g) * 3;

    for (int i = 0; i < ROWS_PER_WAVE; i += 8) {
        const float a0 = xp[0],  a1 = xp[1],  a2 = xp[2];    // row i+g
        const float c0 = xp[12], c1 = xp[13], c2 = xp[14];   // row i+4+g
        xp += 24;
        const v2f a0v = {a0,a0}, a1v = {a1,a1}, a2v = {a2,a2};
        const v2f c0v = {c0,c0}, c1v = {c1,c1}, c2v = {c2,c2};

        v2f eqA[2], eqB[2];
#pragma unroll
        for (int p = 0; p < 2; ++p) {
            v2f sA = PKFMA(a0v, wq0p[p], PKFMA(a1v, wq1p[p], PKFMA(a2v, wq2p[p], bqp[p])));
            v2f sB = PKFMA(c0v, wq0p[p], PKFMA(c1v, wq1p[p], PKFMA(c2v, wq2p[p], bqp[p])));
            eqA[p] = (v2f){exp2_fast(sA.x), exp2_fast(sA.y)};
            eqB[p] = (v2f){exp2_fast(sB.x), exp2_fast(sB.y)};
        }
        v2f tA = eqA[0] + eqA[1];
        v2f tB = eqB[0] + eqB[1];
        float rsA = tA.x + tA.y;
        float rsB = tB.x + tB.y;
        rsA += __shfl_xor(rsA, 1);  rsB += __shfl_xor(rsB, 1);
        rsA += __shfl_xor(rsA, 2);  rsB += __shfl_xor(rsB, 2);
        rsA += __shfl_xor(rsA, 4);  rsB += __shfl_xor(rsB, 4);
        rsA += __shfl_xor(rsA, 8);  rsB += __shfl_xor(rsB, 8);
        const float invA = rcp_fast(rsA);
        const float invB = rcp_fast(rsB);
        const v2f invAv = {invA, invA}, invBv = {invB, invB};

#pragma unroll
        for (int p = 0; p < 2; ++p) {
            accqp[p] = PKFMA(eqA[p], invAv, PKFMA(eqB[p], invBv, accqp[p]));
            v2f sKA = PKFMA(a0v, wk0p[p], PKFMA(a1v, wk1p[p], PKFMA(a2v, wk2p[p], bkp[p])));
            v2f sKB = PKFMA(c0v, wk0p[p], PKFMA(c1v, wk1p[p], PKFMA(c2v, wk2p[p], bkp[p])));
            v2f eA = (v2f){exp2_fast(sKA.x), exp2_fast(sKA.y)};
            v2f eB = (v2f){exp2_fast(sKB.x), exp2_fast(sKB.y)};
            ekp[p] += eA + eB;
            ex0p[p] = PKFMA(eA, a0v, PKFMA(eB, c0v, ex0p[p]));
            ex1p[p] = PKFMA(eA, a1v, PKFMA(eB, c1v, ex1p[p]));
            ex2p[p] = PKFMA(eA, a2v, PKFMA(eB, c2v, ex2p[p]));
        }
    }

    __shared__ float lds[4][PART];
    if (g == 0) {
        // note: redg computed inside g==0 branch is WRONG (shfl needs all lanes);
        // do reductions before branching below.
    }
    // reduce across the 4 row-groups (all 64 lanes participate)
#pragma unroll
    for (int p = 0; p < 2; ++p) {
        accqp[p].x = redg(accqp[p].x); accqp[p].y = redg(accqp[p].y);
        ekp[p].x   = redg(ekp[p].x);   ekp[p].y   = redg(ekp[p].y);
        ex0p[p].x  = redg(ex0p[p].x);  ex0p[p].y  = redg(ex0p[p].y);
        ex1p[p].x  = redg(ex1p[p].x);  ex1p[p].y  = redg(ex1p[p].y);
        ex2p[p].x  = redg(ex2p[p].x);  ex2p[p].y  = redg(ex2p[p].y);
    }
    if (g == 0) {
#pragma unroll
        for (int p = 0; p < 2; ++p) {
            const int klo = sub + 32 * p, khi = klo + 16;
            lds[w][klo]        = accqp[p].x; lds[w][khi]        = accqp[p].y;
            lds[w][64 + klo]   = ekp[p].x;   lds[w][64 + khi]   = ekp[p].y;
            lds[w][128 + klo]  = ex0p[p].x;  lds[w][128 + khi]  = ex0p[p].y;
            lds[w][192 + klo]  = ex1p[p].x;  lds[w][192 + khi]  = ex1p[p].y;
            lds[w][256 + klo]  = ex2p[p].x;  lds[w][256 + khi]  = ex2p[p].y;
        }
    }
    __syncthreads();

    // strided: PART (320) > blockDim (256) — must loop (R2 lesson)
    float* op = ws + (size_t)blk * PART;
    for (int idx = tid; idx < PART; idx += 256)
        op[idx] = lds[0][idx] + lds[1][idx] + lds[2][idx] + lds[3][idx];
}

// Finisher (R1-proven): one 64-thread block per b. Sum SPLIT slices per half,
// apply Wv, combine halves, L2-normalize.
__global__ __launch_bounds__(64) void ea_final(
    const float* __restrict__ ws,
    const float* __restrict__ Wv, const float* __restrict__ bv,
    float* __restrict__ out)
{
    const int b = blockIdx.x;
    const int lane = threadIdx.x;  // = k

    float wv[9], bvv[3];
#pragma unroll
    for (int i = 0; i < 9; ++i) wv[i] = Wv[i];
#pragma unroll
    for (int i = 0; i < 3; ++i) bvv[i] = bv[i];

    float res[2][3];
#pragma unroll
    for (int h = 0; h < 2; ++h) {
        float aq = 0.f, ekk = 0.f, e0 = 0.f, e1 = 0.f, e2 = 0.f;
#pragma unroll
        for (int s = 0; s < SPLIT; ++s) {
            const float* p = ws + (size_t)((b * 2 + h) * SPLIT + s) * PART;
            aq  += p[lane];
            ekk += p[64 + lane];
            e0  += p[128 + lane];
            e1  += p[192 + lane];
            e2  += p[256 + lane];
        }
        const float r = aq / ((float)NHALF * ekk);
        float cv0 = fmaf(e0, wv[0], fmaf(e1, wv[3], fmaf(e2, wv[6], bvv[0] * ekk)));
        float cv1 = fmaf(e0, wv[1], fmaf(e1, wv[4], fmaf(e2, wv[7], bvv[1] * ekk)));
        float cv2 = fmaf(e0, wv[2], fmaf(e1, wv[5], fmaf(e2, wv[8], bvv[2] * ekk)));
        float p0 = r * cv0, p1 = r * cv1, p2 = r * cv2;
        for (int m = 1; m < 64; m <<= 1) {
            p0 += __shfl_xor(p0, m);
            p1 += __shfl_xor(p1, m);
            p2 += __shfl_xor(p2, m);
        }
        res[h][0] = p0; res[h][1] = p1; res[h][2] = p2;
    }

    const float a0 = 0.5f * (res[0][0] + res[1][0]);
    const float a1 = 0.5f * (res[0][1] + res[1][1]);
    const float a2 = 0.5f * (res[0][2] + res[1][2]);
    const float nrm = rsqrtf(fmaf(a0, a0, fmaf(a1, a1, a2 * a2)));
    if (lane == 0) {
        out[(size_t)b * 3 + 0] = a0 * nrm;
        out[(size_t)b * 3 + 1] = a1 * nrm;
        out[(size_t)b * 3 + 2] = a2 * nrm;
    }
}

extern "C" void kernel_launch(void* const* d_in, const int* in_sizes, int n_in,
                              void* d_out, int out_size, void* d_ws, size_t ws_size,
                              hipStream_t stream) {
    const float* inp = (const float*)d_in[0];
    const float* Wq  = (const float*)d_in[1];
    const float* bq  = (const float*)d_in[2];
    const float* Wk  = (const float*)d_in[3];
    const float* bk  = (const float*)d_in[4];
    const float* Wv  = (const float*)d_in[5];
    const float* bv  = (const float*)d_in[6];
    float* ws  = (float*)d_ws;
    float* out = (float*)d_out;

    hipLaunchKernelGGL(ea_partial_pk, dim3(NBLK), dim3(256), 0, stream,
                       inp, Wq, bq, Wk, bk, ws);
    hipLaunchKernelGGL(ea_final, dim3(BATCH), dim3(64), 0, stream,
                       ws, Wv, bv, out);
}

// Round 6
// 99.181 us; speedup vs baseline: 3.1117x; 1.0283x over previous
//
#include <hip/hip_runtime.h>
#include <math.h>

#define BATCH 256
#define NHALF 2048
#define DK 64
#define SPLIT 4
#define NBLK (BATCH * 2 * SPLIT)            // 2048
#define ROWS_PER_BLOCK (NHALF / SPLIT)      // 512
#define ROWS_PER_WAVE  (ROWS_PER_BLOCK / 4) // 128
#define PART 320

typedef float v2f __attribute__((ext_vector_type(2)));
#define PKFMA(a, b, c) __builtin_elementwise_fma((a), (b), (c))

__device__ __forceinline__ float rcp_fast(float x)  { return __builtin_amdgcn_rcpf(x); }
__device__ __forceinline__ float exp2_fast(float x) { return __builtin_amdgcn_exp2f(x); }

// DPP16 rotate-reduce step within each 16-lane row: x += row_ror:N(x).
// Pure VALU (v_add_f32_dpp after DPPCombine) — replaces ds_swizzle shuffles
// in the hot loop (DS pipe + lgkm wait chain was the R5 stall).
template<int ROR>
__device__ __forceinline__ float dpp_ror_add(float x) {
    int t = __builtin_amdgcn_update_dpp(0, __builtin_bit_cast(int, x),
                                        0x120 + ROR, 0xf, 0xf, true);
    return x + __builtin_bit_cast(float, t);
}
__device__ __forceinline__ float rowsum16(float x) {   // sum over 16-lane row
    x = dpp_ror_add<8>(x);
    x = dpp_ror_add<4>(x);
    x = dpp_ror_add<2>(x);
    x = dpp_ror_add<1>(x);
    return x;
}
__device__ __forceinline__ float redg(float v) {       // across the 4 row-groups
    v += __shfl_xor(v, 16);
    v += __shfl_xor(v, 32);
    return v;
}

// Partial kernel: per (b, half, slice) block (2048 blocks x 256 thr = 4 waves).
// 16 lanes per row; lane owns k = sub+16j, j packed in pairs as float2 so
// logits/accums use v_pk_fma_f32. 8 rows/iter (two independent chains).
// Accumulates per k: accq = sum_n softmax_k(q); ek = sum_n exp(k);
// ex[d] = sum_n exp(k)*x[d] (Wv applied in finisher). log2e folded into
// weights so exp = raw v_exp_f32. No inter-block fences (R3 lesson).
__global__ __launch_bounds__(256, 6) void ea_partial_pk(
    const float* __restrict__ inp,
    const float* __restrict__ Wq, const float* __restrict__ bq,
    const float* __restrict__ Wk, const float* __restrict__ bk,
    float* __restrict__ ws)
{
    const int blk   = blockIdx.x;
    const int b     = blk >> 3;
    const int rem   = blk & 7;
    const int half  = rem >> 2;
    const int slice = rem & 3;

    const int tid  = threadIdx.x;
    const int w    = tid >> 6;
    const int lane = tid & 63;
    const int g    = lane >> 4;
    const int sub  = lane & 15;

    const float LOG2E = 1.4426950408889634f;
    v2f wq0p[2], wq1p[2], wq2p[2], bqp[2];
    v2f wk0p[2], wk1p[2], wk2p[2], bkp[2];
#pragma unroll
    for (int p = 0; p < 2; ++p) {
        const int klo = sub + 32 * p, khi = klo + 16;
        wq0p[p] = (v2f){Wq[klo],       Wq[khi]}       * LOG2E;
        wq1p[p] = (v2f){Wq[64 + klo],  Wq[64 + khi]}  * LOG2E;
        wq2p[p] = (v2f){Wq[128 + klo], Wq[128 + khi]} * LOG2E;
        bqp[p]  = (v2f){bq[klo],       bq[khi]}       * LOG2E;
        wk0p[p] = (v2f){Wk[klo],       Wk[khi]}       * LOG2E;
        wk1p[p] = (v2f){Wk[64 + klo],  Wk[64 + khi]}  * LOG2E;
        wk2p[p] = (v2f){Wk[128 + klo], Wk[128 + khi]} * LOG2E;
        bkp[p]  = (v2f){bk[klo],       bk[khi]}       * LOG2E;
    }

    v2f accqp[2] = {{0,0},{0,0}}, ekp[2] = {{0,0},{0,0}};
    v2f ex0p[2] = {{0,0},{0,0}}, ex1p[2] = {{0,0},{0,0}}, ex2p[2] = {{0,0},{0,0}};

    const float* xp = inp
        + ((size_t)b * (2 * NHALF) + (size_t)half * NHALF
           + (size_t)slice * ROWS_PER_BLOCK + (size_t)w * ROWS_PER_WAVE + g) * 3;

    for (int i = 0; i < ROWS_PER_WAVE; i += 8) {
        const float a0 = xp[0],  a1 = xp[1],  a2 = xp[2];    // row i+g
        const float c0 = xp[12], c1 = xp[13], c2 = xp[14];   // row i+4+g
        xp += 24;
        const v2f a0v = {a0,a0}, a1v = {a1,a1}, a2v = {a2,a2};
        const v2f c0v = {c0,c0}, c1v = {c1,c1}, c2v = {c2,c2};

        v2f eqA[2], eqB[2];
#pragma unroll
        for (int p = 0; p < 2; ++p) {
            v2f sA = PKFMA(a0v, wq0p[p], PKFMA(a1v, wq1p[p], PKFMA(a2v, wq2p[p], bqp[p])));
            v2f sB = PKFMA(c0v, wq0p[p], PKFMA(c1v, wq1p[p], PKFMA(c2v, wq2p[p], bqp[p])));
            eqA[p] = (v2f){exp2_fast(sA.x), exp2_fast(sA.y)};
            eqB[p] = (v2f){exp2_fast(sB.x), exp2_fast(sB.y)};
        }
        v2f tA = eqA[0] + eqA[1];
        v2f tB = eqB[0] + eqB[1];
        // 16-lane row softmax denominators via DPP rotate-reduce (VALU only)
        const float rsA = rowsum16(tA.x + tA.y);
        const float rsB = rowsum16(tB.x + tB.y);
        const float invA = rcp_fast(rsA);
        const float invB = rcp_fast(rsB);
        const v2f invAv = {invA, invA}, invBv = {invB, invB};

#pragma unroll
        for (int p = 0; p < 2; ++p) {
            accqp[p] = PKFMA(eqA[p], invAv, PKFMA(eqB[p], invBv, accqp[p]));
            v2f sKA = PKFMA(a0v, wk0p[p], PKFMA(a1v, wk1p[p], PKFMA(a2v, wk2p[p], bkp[p])));
            v2f sKB = PKFMA(c0v, wk0p[p], PKFMA(c1v, wk1p[p], PKFMA(c2v, wk2p[p], bkp[p])));
            v2f eA = (v2f){exp2_fast(sKA.x), exp2_fast(sKA.y)};
            v2f eB = (v2f){exp2_fast(sKB.x), exp2_fast(sKB.y)};
            ekp[p] += eA + eB;
            ex0p[p] = PKFMA(eA, a0v, PKFMA(eB, c0v, ex0p[p]));
            ex1p[p] = PKFMA(eA, a1v, PKFMA(eB, c1v, ex1p[p]));
            ex2p[p] = PKFMA(eA, a2v, PKFMA(eB, c2v, ex2p[p]));
        }
    }

    // reduce across the 4 row-groups (all 64 lanes participate; outside hot loop)
#pragma unroll
    for (int p = 0; p < 2; ++p) {
        accqp[p].x = redg(accqp[p].x); accqp[p].y = redg(accqp[p].y);
        ekp[p].x   = redg(ekp[p].x);   ekp[p].y   = redg(ekp[p].y);
        ex0p[p].x  = redg(ex0p[p].x);  ex0p[p].y  = redg(ex0p[p].y);
        ex1p[p].x  = redg(ex1p[p].x);  ex1p[p].y  = redg(ex1p[p].y);
        ex2p[p].x  = redg(ex2p[p].x);  ex2p[p].y  = redg(ex2p[p].y);
    }

    __shared__ float lds[4][PART];
    if (g == 0) {
#pragma unroll
        for (int p = 0; p < 2; ++p) {
            const int klo = sub + 32 * p, khi = klo + 16;
            lds[w][klo]        = accqp[p].x; lds[w][khi]        = accqp[p].y;
            lds[w][64 + klo]   = ekp[p].x;   lds[w][64 + khi]   = ekp[p].y;
            lds[w][128 + klo]  = ex0p[p].x;  lds[w][128 + khi]  = ex0p[p].y;
            lds[w][192 + klo]  = ex1p[p].x;  lds[w][192 + khi]  = ex1p[p].y;
            lds[w][256 + klo]  = ex2p[p].x;  lds[w][256 + khi]  = ex2p[p].y;
        }
    }
    __syncthreads();

    // strided: PART (320) > blockDim (256) — must loop (R2 lesson)
    float* op = ws + (size_t)blk * PART;
    for (int idx = tid; idx < PART; idx += 256)
        op[idx] = lds[0][idx] + lds[1][idx] + lds[2][idx] + lds[3][idx];
}

// Finisher (R1-proven): one 64-thread block per b. Sum SPLIT slices per half,
// apply Wv, combine halves, L2-normalize.
__global__ __launch_bounds__(64) void ea_final(
    const float* __restrict__ ws,
    const float* __restrict__ Wv, const float* __restrict__ bv,
    float* __restrict__ out)
{
    const int b = blockIdx.x;
    const int lane = threadIdx.x;  // = k

    float wv[9], bvv[3];
#pragma unroll
    for (int i = 0; i < 9; ++i) wv[i] = Wv[i];
#pragma unroll
    for (int i = 0; i < 3; ++i) bvv[i] = bv[i];

    float res[2][3];
#pragma unroll
    for (int h = 0; h < 2; ++h) {
        float aq = 0.f, ekk = 0.f, e0 = 0.f, e1 = 0.f, e2 = 0.f;
#pragma unroll
        for (int s = 0; s < SPLIT; ++s) {
            const float* p = ws + (size_t)((b * 2 + h) * SPLIT + s) * PART;
            aq  += p[lane];
            ekk += p[64 + lane];
            e0  += p[128 + lane];
            e1  += p[192 + lane];
            e2  += p[256 + lane];
        }
        const float r = aq / ((float)NHALF * ekk);
        float cv0 = fmaf(e0, wv[0], fmaf(e1, wv[3], fmaf(e2, wv[6], bvv[0] * ekk)));
        float cv1 = fmaf(e0, wv[1], fmaf(e1, wv[4], fmaf(e2, wv[7], bvv[1] * ekk)));
        float cv2 = fmaf(e0, wv[2], fmaf(e1, wv[5], fmaf(e2, wv[8], bvv[2] * ekk)));
        float p0 = r * cv0, p1 = r * cv1, p2 = r * cv2;
        for (int m = 1; m < 64; m <<= 1) {
            p0 += __shfl_xor(p0, m);
            p1 += __shfl_xor(p1, m);
            p2 += __shfl_xor(p2, m);
        }
        res[h][0] = p0; res[h][1] = p1; res[h][2] = p2;
    }

    const float a0 = 0.5f * (res[0][0] + res[1][0]);
    const float a1 = 0.5f * (res[0][1] + res[1][1]);
    const float a2 = 0.5f * (res[0][2] + res[1][2]);
    const float nrm = rsqrtf(fmaf(a0, a0, fmaf(a1, a1, a2 * a2)));
    if (lane == 0) {
        out[(size_t)b * 3 + 0] = a0 * nrm;
        out[(size_t)b * 3 + 1] = a1 * nrm;
        out[(size_t)b * 3 + 2] = a2 * nrm;
    }
}

extern "C" void kernel_launch(void* const* d_in, const int* in_sizes, int n_in,
                              void* d_out, int out_size, void* d_ws, size_t ws_size,
                              hipStream_t stream) {
    const float* inp = (const float*)d_in[0];
    const float* Wq  = (const float*)d_in[1];
    const float* bq  = (const float*)d_in[2];
    const float* Wk  = (const float*)d_in[3];
    const float* bk  = (const float*)d_in[4];
    const float* Wv  = (const float*)d_in[5];
    const float* bv  = (const float*)d_in[6];
    float* ws  = (float*)d_ws;
    float* out = (float*)d_out;

    hipLaunchKernelGGL(ea_partial_pk, dim3(NBLK), dim3(256), 0, stream,
                       inp, Wq, bq, Wk, bk, ws);
    hipLaunchKernelGGL(ea_final, dim3(BATCH), dim3(64), 0, stream,
                       ws, Wv, bv, out);
}